// Round 14
// baseline (39.445 us; speedup 1.0000x reference)
//
#include <hip/hip_runtime.h>
#include <hip/hip_bf16.h>

// Problem constants: B=1, N=1024, T=2048, E=16384, K=32.
#define TT  2048
#define KK  32
#define NN  1024
#define EE  16384
#define CAP 64     // per-row expert cap (Poisson(16); P(>64) ~ 1e-21)
#define RS  2080   // padded bf16 row stride: [32 causal zeros | 2048 row]

typedef short short8  __attribute__((ext_vector_type(8)));
typedef float f32x4   __attribute__((ext_vector_type(4)));

// Device-global prepped data (rewritten every call).
__device__ short g_xbf[NN * RS];      // 4.26 MB padded bf16 x rows
__device__ short g_krev[EE * 256];    // 8.39 MB: per expert [2 variants][128]
                                      //   var v, entry j = krev[j+v]; krev[i]=tap[47-i]
                                      //   (zero outside i in [16,48)); [64..128) of each
                                      //   variant is zero (b2 null-redirect target).

__device__ __forceinline__ short f2bf(float f) {
    __hip_bfloat16 h = __float2bfloat16(f);
    return __builtin_bit_cast(short, h);
}

// Prep A: blocks 0..1023: x row -> padded bf16; block 1024: zero cnt;
// blocks 1025..5120: tap tables (4 waves/block, 1 expert/wave).
__global__ __launch_bounds__(256) void cvt_kernel(const float* __restrict__ x,
                                                  const float* __restrict__ kern,
                                                  int* __restrict__ cnt) {
    const int bid = blockIdx.x, tid = threadIdx.x;
    if (bid < NN) {
        const float4* xr = (const float4*)(x + (size_t)bid * TT);
        const float4 u = xr[2 * tid], v = xr[2 * tid + 1];
        short8 h;
        h[0]=f2bf(u.x); h[1]=f2bf(u.y); h[2]=f2bf(u.z); h[3]=f2bf(u.w);
        h[4]=f2bf(v.x); h[5]=f2bf(v.y); h[6]=f2bf(v.z); h[7]=f2bf(v.w);
        *(short8*)&g_xbf[(size_t)bid * RS + 32 + 8 * tid] = h;
        if (tid < 4) {
            short8 z; z[0]=0;z[1]=0;z[2]=0;z[3]=0;z[4]=0;z[5]=0;z[6]=0;z[7]=0;
            *(short8*)&g_xbf[(size_t)bid * RS + 8 * tid] = z;   // causal halo
        }
    } else if (bid == NN) {
        ((int4*)cnt)[tid] = make_int4(0, 0, 0, 0);              // 4 KB
    } else {
        // Tap tables: expert e = (bid-1025)*4 + wave; lane j in [0,64).
        const int v = tid >> 6, j = tid & 63;
        const int e = (bid - NN - 1) * 4 + v;
        const float* kp = kern + (size_t)e * KK;
        short v0 = 0, v1 = 0;
        if (j >= 16 && j < 48) v0 = f2bf(kp[47 - j]);   // var0[j] = krev[j]
        if (j >= 15 && j < 47) v1 = f2bf(kp[46 - j]);   // var1[j] = krev[j+1]
        short* kb = g_krev + ((size_t)e << 8);
        kb[j]       = v0;
        kb[64 + j]  = 0;
        kb[128 + j] = v1;
        kb[192 + j] = 0;
    }
}

// Prep B: routing CSR. slots[d*CAP+p] packs (src<<14)|e.
__global__ __launch_bounds__(256) void csr_kernel(const int* __restrict__ src,
                                                  const int* __restrict__ dst,
                                                  int* __restrict__ cnt,
                                                  unsigned* __restrict__ slots) {
    const int e = blockIdx.x * 256 + threadIdx.x;   // 16384 threads
    const int d = dst[e];
    const int p = atomicAdd(&cnt[d], 1);
    if (p < CAP) slots[(size_t)d * CAP + p] = ((unsigned)src[e] << 14) | (unsigned)e;
}

// Main: grid 4096 = (row n, t-quarter w) x 128 thr = 2 parity waves (R13 shape).
// Visit = 6 global b128 loads + 4 MFMA. ZERO LDS in the loop:
//   A-frags (verified R12): rb = g_xbf + s0*RS + t0 + 16c + 8g; +16/+256/+272.
//   B-frags via g_krev: idx = 15-c+8g; p = idx&1; variant base kb = e*256 + p*128;
//     b1 = kb[idx-p .. +8)            == krev[idx..idx+8)   (verified == kt b1)
//     b2 = kb[idx-p+16 .. +24)        == krev[idx+16..+24)  (verified == kt b2)
//     g<2 lanes redirect b2 to kb[96..104) = zeros (the REQUIRED k<16 zeroing).
//   D: col=c=lane&15, row=4g+qd -> t = 512w + 256s + 64g + 16qd + c.
__global__ __launch_bounds__(128, 4) void lti_kernel(
    const float*    __restrict__ x,      // [N, T] fp32 (epilogue skip-connection)
    const int*      __restrict__ cnt,    // [N]
    const unsigned* __restrict__ slots,  // [N, CAP]
    float*          __restrict__ out)    // [N, T]
{
    const int bid = blockIdx.x;
    const int n   = bid >> 2;        // row
    const int w   = bid & 3;         // t-quarter
    const int tid = threadIdx.x;
    const int pw  = tid >> 6;        // parity wave 0..1
    const int ln  = tid & 63;
    const int c   = ln & 15, g = ln >> 4;
    const int t0  = 512 * w;
    const int D   = 16 * c + 8 * g;  // A-fragment offset within the quarter

    __shared__ __align__(16) float red[512];   // parity-1 partials
    __shared__ unsigned bl[CAP];

    if (tid < CAP) bl[tid] = slots[(size_t)n * CAP + tid];
    int L = cnt[n]; if (L > CAP) L = CAP;
    __syncthreads();

    const int M = (L - pw + 1) >> 1;         // this wave's visit count
    #define IDX(I) (pw + 2 * (I))

    const int idx   = 15 - c + 8 * g;
    const int par   = idx & 1;
    const int koff1 = idx - par;                    // even -> 4B-aligned
    const int koff2 = (g < 2) ? 96 : koff1 + 16;    // zero-region redirect for g<2
    const int kvar  = par << 7;

    f32x4 acc0 = {0,0,0,0}, acc1 = {0,0,0,0};
    short8 xa0A, xb0A, xa1A, xb1A, kb1A, kb2A;
    short8 xa0B, xb0B, xa1B, xb1B, kb1B, kb2B;
    short8 xa0C, xb0C, xa1C, xb1C, kb1C, kb2C;

    #define LOADV(S, P)                                                                \
    {                                                                                  \
        const unsigned sv = bl[P];                                                     \
        const int e0 = __builtin_amdgcn_readfirstlane((int)(sv & 16383u));             \
        const int s0 = __builtin_amdgcn_readfirstlane((int)(sv >> 14));                \
        const short* rb = g_xbf + (size_t)s0 * RS + t0 + D;                            \
        xa0##S = *(const short8*)(rb);                                                 \
        xb0##S = *(const short8*)(rb + 16);                                            \
        xa1##S = *(const short8*)(rb + 256);                                           \
        xb1##S = *(const short8*)(rb + 272);                                           \
        const short* kb = g_krev + ((size_t)e0 << 8) + kvar;                           \
        kb1##S = *(const short8*)(kb + koff1);                                         \
        kb2##S = *(const short8*)(kb + koff2);                                         \
    }

    #define COMPUTE(S)                                                                 \
    {                                                                                  \
        acc0 = __builtin_amdgcn_mfma_f32_16x16x32_bf16(xa0##S, kb1##S, acc0, 0, 0, 0); \
        acc0 = __builtin_amdgcn_mfma_f32_16x16x32_bf16(xb0##S, kb2##S, acc0, 0, 0, 0); \
        acc1 = __builtin_amdgcn_mfma_f32_16x16x32_bf16(xa1##S, kb1##S, acc1, 0, 0, 0); \
        acc1 = __builtin_amdgcn_mfma_f32_16x16x32_bf16(xb1##S, kb2##S, acc1, 0, 0, 0); \
    }

    if (M > 0) {
        LOADV(A, IDX(0));
        if (M > 1) LOADV(B, IDX(1));
        if (M > 2) LOADV(C, IDX(2));
        for (int i = 0; i < M; i += 3) {
            COMPUTE(A);
            if (i + 3 < M) LOADV(A, IDX(i + 3));
            if (i + 1 < M) {
                COMPUTE(B);
                if (i + 4 < M) LOADV(B, IDX(i + 4));
            }
            if (i + 2 < M) {
                COMPUTE(C);
                if (i + 5 < M) LOADV(C, IDX(i + 5));
            }
        }
    }

    // Parity combine (block-uniform control flow; acc==0 when M==0).
    if (pw == 1) {
        #pragma unroll
        for (int qd = 0; qd < 4; ++qd) {
            const int ta = 64 * g + 16 * qd + c;
            red[ta]       = acc0[qd];
            red[256 + ta] = acc1[qd];
        }
    }
    __syncthreads();
    if (pw == 0) {
        const float* xr  = x   + (size_t)n * TT + t0;
        float*       orw = out + (size_t)n * TT + t0;
        #pragma unroll
        for (int qd = 0; qd < 4; ++qd) {
            const int ta = 64 * g + 16 * qd + c;
            orw[ta]       = xr[ta]       + acc0[qd] + red[ta];
            orw[256 + ta] = xr[256 + ta] + acc1[qd] + red[256 + ta];
        }
    }
    #undef IDX
    #undef LOADV
    #undef COMPUTE
}

extern "C" void kernel_launch(void* const* d_in, const int* in_sizes, int n_in,
                              void* d_out, int out_size, void* d_ws, size_t ws_size,
                              hipStream_t stream) {
    const float* x    = (const float*)d_in[0];
    const float* kern = (const float*)d_in[1];
    const int*   src  = (const int*)d_in[2];
    const int*   dst  = (const int*)d_in[3];
    float*       out  = (float*)d_out;

    int*      cnt   = (int*)d_ws;                       // 4 KB
    unsigned* slots = (unsigned*)((char*)d_ws + 4096);  // 256 KB

    cvt_kernel<<<dim3(NN + 1 + EE / 4), dim3(256), 0, stream>>>(x, kern, cnt);
    csr_kernel<<<dim3(EE / 256), dim3(256), 0, stream>>>(src, dst, cnt, slots);
    lti_kernel<<<dim3(NN * 4), dim3(128), 0, stream>>>(x, cnt, slots, out);
}

// Round 16
// 34.630 us; speedup vs baseline: 1.1390x; 1.1390x over previous
//
#include <hip/hip_runtime.h>
#include <hip/hip_bf16.h>

// Problem constants: B=1, N=1024, T=2048, E=16384, K=32.
#define TT  2048
#define KK  32
#define NN  1024
#define EE  16384
#define CAP 64     // per-row expert cap (Poisson(16); P(>64) ~ 1e-21)
#define RS  2080   // padded bf16 row stride: [32 causal zeros | 2048 row]

typedef short short8 __attribute__((ext_vector_type(8)));
typedef float f32x4  __attribute__((ext_vector_type(4)));

// Padded bf16 x rows (device global, rewritten every call).
__device__ short g_xbf[NN * RS];   // 4.26 MB

__device__ __forceinline__ short f2bf(float f) {
    __hip_bfloat16 h = __float2bfloat16(f);
    return __builtin_bit_cast(short, h);
}

// Async global->LDS DMA, 16 B per ACTIVE lane (dest = uniform base + lane*16).
__device__ __forceinline__ void gload_lds16(const short* g, short* l) {
    __builtin_amdgcn_global_load_lds(
        (const __attribute__((address_space(1))) void*)(const void*)(g),
        (__attribute__((address_space(3))) void*)(void*)(l), 16, 0, 0);
}

// Prep A: blocks 0..1023: x row -> padded bf16 row; block 1024: zero cnt.
__global__ __launch_bounds__(256) void cvt_kernel(const float* __restrict__ x,
                                                  int* __restrict__ cnt) {
    const int bid = blockIdx.x, tid = threadIdx.x;
    if (bid < NN) {
        const float4* xr = (const float4*)(x + (size_t)bid * TT);
        const float4 u = xr[2 * tid], v = xr[2 * tid + 1];
        short8 h;
        h[0]=f2bf(u.x); h[1]=f2bf(u.y); h[2]=f2bf(u.z); h[3]=f2bf(u.w);
        h[4]=f2bf(v.x); h[5]=f2bf(v.y); h[6]=f2bf(v.z); h[7]=f2bf(v.w);
        *(short8*)&g_xbf[(size_t)bid * RS + 32 + 8 * tid] = h;
        if (tid < 4) {
            short8 z; z[0]=0;z[1]=0;z[2]=0;z[3]=0;z[4]=0;z[5]=0;z[6]=0;z[7]=0;
            *(short8*)&g_xbf[(size_t)bid * RS + 8 * tid] = z;   // causal halo
        }
    } else {
        ((int4*)cnt)[tid] = make_int4(0, 0, 0, 0);              // 4 KB
    }
}

// Prep B: routing CSR. slots[d*CAP+p] packs (src<<14)|e.
__global__ __launch_bounds__(256) void csr_kernel(const int* __restrict__ src,
                                                  const int* __restrict__ dst,
                                                  int* __restrict__ cnt,
                                                  unsigned* __restrict__ slots) {
    const int e = blockIdx.x * 256 + threadIdx.x;   // 16384 threads
    const int d = dst[e];
    const int p = atomicAdd(&cnt[d], 1);
    if (p < CAP) slots[(size_t)d * CAP + p] = ((unsigned)src[e] << 14) | (unsigned)e;
}

// Main: grid 1024 (row n), 128 thr = 2 parity waves. ONE VISIT = ONE EXPERT OVER
// THE FULL ROW (16384 visits total, 4x fewer than all prior rounds). Per visit:
//   cluster = EXACTLY 6 VMEM {5x gload_lds (whole 4160B padded row, halo baked
//   in), 1x fp32 tap float4}; 3-deep rotation, counted vmcnt(12/6/0).
//   Then: kt commit (4 b16 writes), b1/b2 ds_reads ONCE (reused across the whole
//   row), 8 segments x {2 ds_read_b128 A-frags + 2 MFMA}.
// Verified MFMA math (R2-R13), full-row buffer xsb = padded row:
//   A1 b128 at xsb[256s + 16c + 8g], A2 at +16, s in [0,8)
//   b1 = kt[a][s1..+8), b2 = kt[a][s1+16..+24) with g<2 -> 0 (REQUIRED)
//   kt[a][((a+1)&7)+47-m] = tap[m];  a=c&7, s1=((a+1)&7)+15-c+8g (8-aligned)
//   D: col=c=lane&15, row=4g+qd -> t = 256s + 64g + 16qd + c
__global__ __launch_bounds__(128, 2) void lti_kernel(
    const float*    __restrict__ x,      // [N, T] fp32 (skip-connection + taps src)
    const float*    __restrict__ kern,   // [E, K] fp32
    const int*      __restrict__ cnt,    // [N]
    const unsigned* __restrict__ slots,  // [N, CAP]
    float*          __restrict__ out)    // [N, T]
{
    const int n   = blockIdx.x;
    const int tid = threadIdx.x;
    const int pw  = tid >> 6;        // parity wave 0..1
    const int ln  = tid & 63;
    const int c   = ln & 15, g = ln >> 4;
    const int D   = 16 * c + 8 * g;

    __shared__ __align__(16) short xs_all[2][3][RS];  // 2 waves x 3 bufs x 4160 B
    __shared__ __align__(16) short kt_all[2][8][72];  // per-wave shifted taps table
    __shared__ __align__(16) float red[TT];           // parity-1 partials (8 KB)
    __shared__ unsigned bl[CAP];

    short (*xsb)[RS] = xs_all[pw];
    short (*kt)[72]  = kt_all[pw];

    short8 z8; z8[0]=0;z8[1]=0;z8[2]=0;z8[3]=0;z8[4]=0;z8[5]=0;z8[6]=0;z8[7]=0;

    {   // per-wave init: zero own taps table (pads persist across experts)
        short8* kz = (short8*)&kt[0][0];   // 576 shorts = 72 short8
        kz[ln] = z8;
        if (ln < 8) kz[64 + ln] = z8;
    }
    if (tid < CAP) bl[tid] = slots[(size_t)n * CAP + tid];
    int L = cnt[n]; if (L > CAP) L = CAP;
    __syncthreads();

    const int M = (L - pw + 1) >> 1;         // this wave's visit count
    #define IDX(I) (pw + 2 * (I))

    f32x4 acc[8];
    #pragma unroll
    for (int s = 0; s < 8; ++s) { acc[s][0]=0.f; acc[s][1]=0.f; acc[s][2]=0.f; acc[s][3]=0.f; }

    float4 tr0, tr1, tr2;                    // tap regs per stage

    const int a_ = c & 7;
    const int s1 = ((a_ + 1) & 7) + 15 - c + 8 * g;   // b128-aligned by construction

    // Cluster: EXACTLY 6 VMEM ops (5 DMA staging the whole padded row + 1 tap).
    #define ISSUE(S, P)                                                                \
    {                                                                                  \
        const unsigned sv = bl[P];                                                     \
        const int e0 = __builtin_amdgcn_readfirstlane((int)(sv & 16383u));             \
        const int s0 = __builtin_amdgcn_readfirstlane((int)(sv >> 14));                \
        const short* rb = g_xbf + (size_t)s0 * RS;                                     \
        gload_lds16(rb + 8 * ln,        &xsb[S][0]);                                   \
        gload_lds16(rb + 8 * ln + 512,  &xsb[S][512]);                                 \
        gload_lds16(rb + 8 * ln + 1024, &xsb[S][1024]);                                \
        gload_lds16(rb + 8 * ln + 1536, &xsb[S][1536]);                                \
        if (ln < 4) gload_lds16(rb + 8 * ln + 2048, &xsb[S][2048]);                    \
        tr##S = *(const float4*)(kern + ((size_t)e0 << 5) + 4 * (ln & 7));             \
    }

    #define COMMIT(S)                                                                  \
    {                                                                                  \
        const int a2 = ln >> 3, pad = (a2 + 1) & 7, mb = 4 * (ln & 7);                 \
        kt[a2][pad + 47 - mb] = f2bf(tr##S.x);                                         \
        kt[a2][pad + 46 - mb] = f2bf(tr##S.y);                                         \
        kt[a2][pad + 45 - mb] = f2bf(tr##S.z);                                         \
        kt[a2][pad + 44 - mb] = f2bf(tr##S.w);                                         \
    }

    #define COMPUTE(S)                                                                 \
    {                                                                                  \
        const short8 b1 = *(const short8*)&kt[a_][s1];                                 \
        short8 b2 = *(const short8*)&kt[a_][s1 + 16];                                  \
        if (g < 2) b2 = z8;   /* k<16 zeroing is REQUIRED */                           \
        _Pragma("unroll")                                                              \
        for (int s = 0; s < 8; ++s) {                                                  \
            const short8 a1  = *(const short8*)&xsb[S][256 * s + D];                   \
            const short8 a2v = *(const short8*)&xsb[S][256 * s + D + 16];              \
            acc[s] = __builtin_amdgcn_mfma_f32_16x16x32_bf16(a1,  b1, acc[s], 0,0,0);  \
            acc[s] = __builtin_amdgcn_mfma_f32_16x16x32_bf16(a2v, b2, acc[s], 0,0,0);  \
        }                                                                              \
    }

    // BODY: issue visit I+2's cluster, wait for visit I's cluster, commit+compute.
    #define BODY(SC, SN, I)                                                            \
    if ((I) < M) {                                                                     \
        __builtin_amdgcn_sched_barrier(0);                                             \
        if ((I) + 2 < M) ISSUE(SN, IDX((I) + 2));                                      \
        const int rem = M - (I);                                                       \
        if (rem >= 3)      { asm volatile("s_waitcnt vmcnt(12)" ::: "memory"); }       \
        else if (rem == 2) { asm volatile("s_waitcnt vmcnt(6)"  ::: "memory"); }       \
        else               { asm volatile("s_waitcnt vmcnt(0)"  ::: "memory"); }       \
        __builtin_amdgcn_sched_barrier(0);                                             \
        COMMIT(SC);                                                                    \
        COMPUTE(SC);                                                                   \
    }

    if (M > 0) ISSUE(0, IDX(0));
    if (M > 1) ISSUE(1, IDX(1));
    for (int i = 0; i < M; i += 3) {
        BODY(0, 2, i);
        BODY(1, 0, i + 1);
        BODY(2, 1, i + 2);
    }

    // Parity combine (block-uniform control flow; acc==0 when M==0).
    if (pw == 1) {
        #pragma unroll
        for (int s = 0; s < 8; ++s)
            #pragma unroll
            for (int qd = 0; qd < 4; ++qd)
                red[256 * s + 64 * g + 16 * qd + c] = acc[s][qd];
    }
    __syncthreads();
    if (pw == 0) {
        const float* xr  = x   + (size_t)n * TT;
        float*       orw = out + (size_t)n * TT;
        #pragma unroll
        for (int s = 0; s < 8; ++s) {
            #pragma unroll
            for (int qd = 0; qd < 4; ++qd) {
                const int ta = 256 * s + 64 * g + 16 * qd + c;
                orw[ta] = xr[ta] + acc[s][qd] + red[ta];
            }
        }
    }
    #undef IDX
    #undef ISSUE
    #undef COMMIT
    #undef COMPUTE
    #undef BODY
}

extern "C" void kernel_launch(void* const* d_in, const int* in_sizes, int n_in,
                              void* d_out, int out_size, void* d_ws, size_t ws_size,
                              hipStream_t stream) {
    const float* x    = (const float*)d_in[0];
    const float* kern = (const float*)d_in[1];
    const int*   src  = (const int*)d_in[2];
    const int*   dst  = (const int*)d_in[3];
    float*       out  = (float*)d_out;

    int*      cnt   = (int*)d_ws;                       // 4 KB
    unsigned* slots = (unsigned*)((char*)d_ws + 4096);  // 256 KB

    cvt_kernel<<<dim3(NN + 1), dim3(256), 0, stream>>>(x, cnt);
    csr_kernel<<<dim3(EE / 256), dim3(256), 0, stream>>>(src, dst, cnt, slots);
    lti_kernel<<<dim3(NN), dim3(128), 0, stream>>>(x, kern, cnt, slots, out);
}